// Round 6
// baseline (1498.233 us; speedup 1.0000x reference)
//
#include <hip/hip_runtime.h>
#include <hip/hip_bf16.h>
#include <stdint.h>

#define EDIM 300
#define KP   320      // padded E for MFMA K-loop
#define HDIM 256
#define G4H  1024
#define NB   2048     // both directions' gates
#define TAGS 9
#define BATCH 64
#define SEQ  512
#define MROWS (SEQ*BATCH)   // 32768

typedef _Float16 f16;
typedef _Float16 half2_t __attribute__((ext_vector_type(2)));
typedef _Float16 half8_t __attribute__((ext_vector_type(8)));
typedef float    floatx4 __attribute__((ext_vector_type(4)));

__device__ __forceinline__ float fdot2(uint32_t w, uint32_t h, float acc) {
#if __has_builtin(__builtin_amdgcn_fdot2)
    return __builtin_amdgcn_fdot2(__builtin_bit_cast(half2_t, w),
                                  __builtin_bit_cast(half2_t, h), acc, false);
#else
    half2_t a = __builtin_bit_cast(half2_t, w), b = __builtin_bit_cast(half2_t, h);
    return acc + (float)a[0]*(float)b[0] + (float)a[1]*(float)b[1];
#endif
}

#define RL(v, l) ((uint32_t)__builtin_amdgcn_readlane((int)(v), (l)))

__device__ __forceinline__ float fast_sigmoid(float x) {
    return __builtin_amdgcn_rcpf(1.f + __expf(-x));
}
__device__ __forceinline__ float fast_tanh(float x) {
    // 1 - 2/(e^{2x}+1); exact at +-inf via rcp(inf)=0
    return 1.f - 2.f*__builtin_amdgcn_rcpf(__expf(2.f*x) + 1.f);
}

// ---- pack input-projection weights [n<1024: wih_f | n>=1024: wih_b], K padded to 320, + fused bias
__global__ void k_pack_wih(const float* __restrict__ wih_f, const float* __restrict__ wih_b,
                           const float* __restrict__ bih_f, const float* __restrict__ bhh_f,
                           const float* __restrict__ bih_b, const float* __restrict__ bhh_b,
                           f16* __restrict__ wpack, float* __restrict__ bias2) {
    int n = blockIdx.x;
    const float* src = (n < G4H) ? (wih_f + (long)n*EDIM) : (wih_b + (long)(n-G4H)*EDIM);
    for (int k = threadIdx.x; k < KP; k += 64)
        wpack[(long)n*KP + k] = (k < EDIM) ? (f16)src[k] : (f16)0.f;
    if (threadIdx.x == 0)
        bias2[n] = (n < G4H) ? (bih_f[n] + bhh_f[n]) : (bih_b[n-G4H] + bhh_b[n-G4H]);
}

// ---- pack recurrent weights into [dir][k2][j][2] f16 (k-pairs for v_dot2, j coalesced)
__global__ void k_pack_whh(const float* __restrict__ whh_f, const float* __restrict__ whh_b,
                           f16* __restrict__ whhp) {
    int fidx = blockIdx.x*256 + threadIdx.x;   // < 524288
    int d  = fidx >> 18;
    int r  = fidx & 262143;
    int k2 = r >> 11;
    int r2 = r & 2047;
    int j  = r2 >> 1;
    int p  = r2 & 1;
    const float* w = d ? whh_b : whh_f;
    whhp[fidx] = (f16)w[(long)j*HDIM + 2*k2 + p];
}

// ---- embedding gather, f16, row m = t*64+b, padded to KP
__global__ void k_gather(const int* __restrict__ sentence, const float* __restrict__ embed,
                         f16* __restrict__ xg) {
    int m = blockIdx.x;
    int t = m >> 6, b = m & 63;
    int tok = sentence[b*SEQ + t];
    const float* row = embed + (long)tok*EDIM;
    for (int e = threadIdx.x; e < KP; e += 64)
        xg[(long)m*KP + e] = (e < EDIM) ? (f16)row[e] : (f16)0.f;
}

// ---- xproj = xg @ wpack^T + bias2, f16 MFMA GEMM, M=32768 N=2048 K=320
__launch_bounds__(256)
__global__ void k_gemm_xproj(const f16* __restrict__ xg, const f16* __restrict__ wpack,
                             const float* __restrict__ bias2, f16* __restrict__ xproj) {
    __shared__ __align__(16) f16 As[128*40];
    __shared__ __align__(16) f16 Bs[128*40];
    int tid = threadIdx.x;
    int bm = blockIdx.x, bn = blockIdx.y;
    int wid = tid >> 6, lane = tid & 63;
    int waveM = wid & 1, waveN = wid >> 1;
    int quad = lane >> 4, mlo = lane & 15;
    floatx4 acc[4][4] = {};
    for (int k0 = 0; k0 < KP; k0 += 32) {
        for (int it = 0; it < 2; ++it) {
            int c = tid + it*256;
            int row = c >> 2, ko = (c & 3)*8;
            *(uint4*)(&As[row*40 + ko]) = *(const uint4*)(&xg[(long)(bm*128+row)*KP + k0 + ko]);
            *(uint4*)(&Bs[row*40 + ko]) = *(const uint4*)(&wpack[(long)(bn*128+row)*KP + k0 + ko]);
        }
        __syncthreads();
        half8_t af[4], bf[4];
        #pragma unroll
        for (int i = 0; i < 4; ++i)
            af[i] = *(const half8_t*)(&As[(waveM*64 + i*16 + mlo)*40 + quad*8]);
        #pragma unroll
        for (int j = 0; j < 4; ++j)
            bf[j] = *(const half8_t*)(&Bs[(waveN*64 + j*16 + mlo)*40 + quad*8]);
        #pragma unroll
        for (int i = 0; i < 4; ++i)
            #pragma unroll
            for (int j = 0; j < 4; ++j)
                acc[i][j] = __builtin_amdgcn_mfma_f32_16x16x32_f16(af[i], bf[j], acc[i][j], 0, 0, 0);
        __syncthreads();
    }
    #pragma unroll
    for (int i = 0; i < 4; ++i)
        #pragma unroll
        for (int j = 0; j < 4; ++j) {
            int col = bn*128 + waveN*64 + j*16 + mlo;
            float bv = bias2[col];
            #pragma unroll
            for (int r = 0; r < 4; ++r) {
                int row = bm*128 + waveM*64 + i*16 + quad*4 + r;
                xproj[(long)row*NB + col] = (f16)(acc[i][j][r] + bv);
            }
        }
}

// ---- LSTM recurrence: WG = (dir, batch), 512 threads, 2 gate rows per thread.
// tid<256: rows (u, u+256) = (i,f); tid>=256: rows (512+u, 768+u) = (g,o).
// amdgpu_waves_per_eu(2,2) pins the allocator's occupancy target at 2 waves/SIMD
// -> 256-VGPR budget, so the 2x96 weight pairs stay truly register-resident.
// Remaining 32 pairs/row in LDS via ds_read_b128. h: 1 ds_read_b128 + readlane
// broadcast shared by both rows. Gate nonlinearities PRE-barrier (wave-uniform).
#define NREG 96
#define NLQ  8      // LDS uint4-quads per row (32 pairs)
__attribute__((amdgpu_waves_per_eu(2, 2)))
__launch_bounds__(512)
__global__ void k_recur(const f16* __restrict__ xproj, const f16* __restrict__ whhp,
                        f16* __restrict__ hcat) {
    __shared__ uint4 wlds[2*NLQ][512];   // 128 KB
    __shared__ uint32_t hpair[128];      // h as f16 pairs
    __shared__ float2 gbuf[512];         // (si,sf) for u<256 | (tg,so) at 256+u
    int dir = blockIdx.x & 1, b = blockIdx.x >> 1;
    int tid = threadIdx.x, lane = tid & 63;
    int u = tid & 255, hs = tid >> 8;    // hs wave-uniform (waves 0-3 vs 4-7)
    int rowA = hs ? (512 + u) : u;       // g : i
    int rowB = rowA + 256;               // o : f
    const uint32_t* base = (const uint32_t*)whhp + (long)dir*131072;
    const uint32_t* wgA = base + rowA;
    const uint32_t* wgB = base + rowB;
    uint32_t wregA[NREG], wregB[NREG];
    #pragma unroll
    for (int i = 0; i < NREG; ++i) { wregA[i] = wgA[(long)i*1024]; wregB[i] = wgB[(long)i*1024]; }
    #pragma unroll
    for (int i = 0; i < NREG; ++i) { asm volatile("" : "+v"(wregA[i]), "+v"(wregB[i])); }
    #pragma unroll
    for (int q = 0; q < NLQ; ++q) {
        uint4 wa, wb;
        wa.x = wgA[(long)(NREG+4*q+0)*1024]; wa.y = wgA[(long)(NREG+4*q+1)*1024];
        wa.z = wgA[(long)(NREG+4*q+2)*1024]; wa.w = wgA[(long)(NREG+4*q+3)*1024];
        wb.x = wgB[(long)(NREG+4*q+0)*1024]; wb.y = wgB[(long)(NREG+4*q+1)*1024];
        wb.z = wgB[(long)(NREG+4*q+2)*1024]; wb.w = wgB[(long)(NREG+4*q+3)*1024];
        wlds[q][tid] = wa;
        wlds[NLQ+q][tid] = wb;
    }
    const f16* xA = xproj + dir*G4H + rowA;
    const f16* xB = xproj + dir*G4H + rowB;
    float c = 0.f;
    if (tid < 128) hpair[tid] = 0u;
    __syncthreads();
    long dstep = dir ? -64 : 64;
    long mrow = (long)((dir ? SEQ-1 : 0)*64 + b);
    float xvA = (float)xA[mrow*NB], xvB = (float)xB[mrow*NB];
    for (int s = 0; s < SEQ; ++s) {
        long mnext = (s+1 < SEQ) ? (mrow + dstep) : mrow;
        float xnA = (float)xA[mnext*NB], xnB = (float)xB[mnext*NB];  // prefetch
        uint4 hq = ((const uint4*)hpair)[lane & 31];   // lane L: pairs 4L..4L+3
        float aA0=0.f, aA1=0.f, aB0=0.f, aB1=0.f;
        #pragma unroll
        for (int qq = 0; qq < NREG/4; ++qq) {          // pairs 0..95 (VGPR weights)
            uint32_t h0 = RL(hq.x, qq), h1 = RL(hq.y, qq);
            uint32_t h2 = RL(hq.z, qq), h3 = RL(hq.w, qq);
            aA0 = fdot2(wregA[4*qq+0], h0, aA0); aB0 = fdot2(wregB[4*qq+0], h0, aB0);
            aA1 = fdot2(wregA[4*qq+1], h1, aA1); aB1 = fdot2(wregB[4*qq+1], h1, aB1);
            aA0 = fdot2(wregA[4*qq+2], h2, aA0); aB0 = fdot2(wregB[4*qq+2], h2, aB0);
            aA1 = fdot2(wregA[4*qq+3], h3, aA1); aB1 = fdot2(wregB[4*qq+3], h3, aB1);
        }
        #pragma unroll
        for (int q = 0; q < NLQ; ++q) {                // pairs 96..127 (LDS weights)
            int qq = NREG/4 + q;
            uint4 wa = wlds[q][tid], wb = wlds[NLQ+q][tid];
            uint32_t h0 = RL(hq.x, qq), h1 = RL(hq.y, qq);
            uint32_t h2 = RL(hq.z, qq), h3 = RL(hq.w, qq);
            aA0 = fdot2(wa.x, h0, aA0); aB0 = fdot2(wb.x, h0, aB0);
            aA1 = fdot2(wa.y, h1, aA1); aB1 = fdot2(wb.y, h1, aB1);
            aA0 = fdot2(wa.z, h2, aA0); aB0 = fdot2(wb.z, h2, aB0);
            aA1 = fdot2(wa.w, h3, aA1); aB1 = fdot2(wb.w, h3, aB1);
        }
        float pA = aA0 + aA1 + xvA;
        float pB = aB0 + aB1 + xvB;
        // Pre-barrier nonlinearities (hs is wave-uniform -> no divergence):
        // hs==0: (sigmoid(i), sigmoid(f));  hs==1: (tanh(g), sigmoid(o))
        float vA = hs ? fast_tanh(pA) : fast_sigmoid(pA);
        float vB = fast_sigmoid(pB);
        gbuf[tid] = make_float2(vA, vB);
        xvA = xnA; xvB = xnB;
        __syncthreads();               // gbuf complete; hq reads done
        f16 hh;
        if (tid < 256) {
            float2 IF = gbuf[tid];         // (si, sf) of unit tid
            float2 GO = gbuf[256 + tid];   // (tg, so) of unit tid
            c = IF.y*c + IF.x*GO.x;
            float h = GO.y*fast_tanh(c);
            hh = (f16)h;
            ((f16*)hpair)[tid] = hh;
        }
        __syncthreads();               // new h visible before next step
        if (tid < 256)
            hcat[mrow*512 + dir*HDIM + tid] = hh;   // store outside serial window
        mrow += dstep;
    }
}

// ---- emissions: one wave per (t,b) row; lanes split K=512; 9 shuffle-reduced dots
__launch_bounds__(256)
__global__ void k_emis(const f16* __restrict__ hcat, const float* __restrict__ w_out,
                       const float* __restrict__ b_out, float* __restrict__ emis) {
    int r = blockIdx.x*4 + (threadIdx.x >> 6);
    int lane = threadIdx.x & 63;
    float hv[8];
    #pragma unroll
    for (int i = 0; i < 8; ++i) hv[i] = (float)hcat[(long)r*512 + lane + i*64];
    for (int tag = 0; tag < TAGS; ++tag) {
        float acc = 0.f;
        #pragma unroll
        for (int i = 0; i < 8; ++i) acc += hv[i]*w_out[tag*512 + lane + i*64];
        for (int off = 32; off; off >>= 1) acc += __shfl_xor(acc, off);
        if (lane == 0) emis[(long)r*TAGS + tag] = acc + b_out[tag];
    }
}

// ---- CRF: one wave per batch row. Gold score (lane-parallel over t) + forward logZ
// (lanes 0..8 hold alpha[j], shuffle-broadcast logsumexp over 9 prev tags).
__launch_bounds__(256)
__global__ void k_crf(const float* __restrict__ emis, const int* __restrict__ tags,
                      const int* __restrict__ mask, const float* __restrict__ start_trans,
                      const float* __restrict__ end_trans, const float* __restrict__ trans,
                      float* __restrict__ out) {
    int b = blockIdx.x*4 + (threadIdx.x >> 6);
    int lane = threadIdx.x & 63;
    int len = 0;
    #pragma unroll
    for (int i = 0; i < 8; ++i) len += mask[b*SEQ + lane + i*64];
    for (int off = 32; off; off >>= 1) len += __shfl_xor(len, off);
    float sc = 0.f;
    for (int i = 0; i < 8; ++i) {
        int t = 1 + lane + i*64;
        if (t < SEQ && mask[b*SEQ + t]) {
            int tp = tags[b*SEQ + t - 1], tc = tags[b*SEQ + t];
            sc += trans[tp*TAGS + tc] + emis[(long)(t*64 + b)*TAGS + tc];
        }
    }
    for (int off = 32; off; off >>= 1) sc += __shfl_xor(sc, off);
    int tag0 = tags[b*SEQ];
    sc += start_trans[tag0] + emis[(long)b*TAGS + tag0];
    sc += end_trans[tags[b*SEQ + len - 1]];
    // logZ
    bool act = lane < TAGS;
    int j = act ? lane : 0;
    float tcol[TAGS];
    #pragma unroll
    for (int i = 0; i < TAGS; ++i) tcol[i] = trans[i*TAGS + j];
    float alpha = act ? (start_trans[j] + emis[(long)b*TAGS + j]) : -1e30f;
    for (int t = 1; t < SEQ; ++t) {
        int mt = mask[b*SEQ + t];
        float em = emis[(long)(t*64 + b)*TAGS + j];
        float v[TAGS], mx = -1e30f;
        #pragma unroll
        for (int i = 0; i < TAGS; ++i) { v[i] = __shfl(alpha, i) + tcol[i]; mx = fmaxf(mx, v[i]); }
        float ss = 0.f;
        #pragma unroll
        for (int i = 0; i < TAGS; ++i) ss += __expf(v[i] - mx);
        float nxt = mx + __logf(ss) + em;
        if (mt && act) alpha = nxt;
    }
    float fv = act ? (alpha + end_trans[j]) : -1e30f;
    float mx = fv;
    for (int off = 32; off; off >>= 1) mx = fmaxf(mx, __shfl_xor(mx, off));
    float ss = act ? __expf(fv - mx) : 0.f;
    for (int off = 32; off; off >>= 1) ss += __shfl_xor(ss, off);
    float logZ = mx + __logf(ss);
    if (lane == 0) atomicAdd(out, (logZ - sc) * (1.0f/BATCH));
}

extern "C" void kernel_launch(void* const* d_in, const int* in_sizes, int n_in,
                              void* d_out, int out_size, void* d_ws, size_t ws_size,
                              hipStream_t stream) {
    const int*   sentence    = (const int*)  d_in[0];
    const int*   tags        = (const int*)  d_in[1];
    const float* embed       = (const float*)d_in[2];
    const float* wih_f       = (const float*)d_in[3];
    const float* whh_f       = (const float*)d_in[4];
    const float* bih_f       = (const float*)d_in[5];
    const float* bhh_f       = (const float*)d_in[6];
    const float* wih_b       = (const float*)d_in[7];
    const float* whh_b       = (const float*)d_in[8];
    const float* bih_b       = (const float*)d_in[9];
    const float* bhh_b       = (const float*)d_in[10];
    const float* w_out       = (const float*)d_in[11];
    const float* b_out       = (const float*)d_in[12];
    const float* start_trans = (const float*)d_in[13];
    const float* end_trans   = (const float*)d_in[14];
    const float* trans       = (const float*)d_in[15];
    const int*   mask        = (const int*)  d_in[16];

    char* ws = (char*)d_ws;
    f16*   xg    = (f16*)ws;   ws += (size_t)MROWS*KP*2;      // 20.97 MB
    f16*   wpack = (f16*)ws;   ws += (size_t)NB*KP*2;         // 1.31 MB
    float* bias2 = (float*)ws; ws += (size_t)NB*4;            // 8 KB
    f16*   whhp  = (f16*)ws;   ws += (size_t)2*262144*2;      // 1.05 MB
    f16*   xproj = (f16*)ws;   ws += (size_t)MROWS*NB*2;      // 134.2 MB
    f16*   hcat  = (f16*)ws;   ws += (size_t)MROWS*512*2;     // 33.55 MB
    float* emis  = (float*)ws; ws += (size_t)MROWS*TAGS*4;    // 1.18 MB

    hipLaunchKernelGGL(k_pack_wih, dim3(NB), dim3(64), 0, stream,
                       wih_f, wih_b, bih_f, bhh_f, bih_b, bhh_b, wpack, bias2);
    hipLaunchKernelGGL(k_pack_whh, dim3(2048), dim3(256), 0, stream, whh_f, whh_b, whhp);
    hipLaunchKernelGGL(k_gather, dim3(MROWS), dim3(64), 0, stream, sentence, embed, xg);
    hipLaunchKernelGGL(k_gemm_xproj, dim3(256,16), dim3(256), 0, stream, xg, wpack, bias2, xproj);
    hipLaunchKernelGGL(k_recur, dim3(128), dim3(512), 0, stream, xproj, whhp, hcat);
    hipLaunchKernelGGL(k_emis, dim3(MROWS/4), dim3(256), 0, stream, hcat, w_out, b_out, emis);
    hipMemsetAsync(d_out, 0, sizeof(float), stream);
    hipLaunchKernelGGL(k_crf, dim3(BATCH/4), dim3(256), 0, stream,
                       emis, tags, mask, start_trans, end_trans, trans, (float*)d_out);
}

// Round 7
// 1372.758 us; speedup vs baseline: 1.0914x; 1.0914x over previous
//
#include <hip/hip_runtime.h>
#include <hip/hip_bf16.h>
#include <stdint.h>

#define EDIM 300
#define KP   320      // padded E for MFMA K-loop
#define HDIM 256
#define G4H  1024
#define NB   2048     // both directions' gates
#define TAGS 9
#define BATCH 64
#define SEQ  512
#define MROWS (SEQ*BATCH)   // 32768

typedef _Float16 f16;
typedef _Float16 half2_t __attribute__((ext_vector_type(2)));
typedef _Float16 half8_t __attribute__((ext_vector_type(8)));
typedef float    floatx4 __attribute__((ext_vector_type(4)));

__device__ __forceinline__ float fdot2(uint32_t w, uint32_t h, float acc) {
#if __has_builtin(__builtin_amdgcn_fdot2)
    return __builtin_amdgcn_fdot2(__builtin_bit_cast(half2_t, w),
                                  __builtin_bit_cast(half2_t, h), acc, false);
#else
    half2_t a = __builtin_bit_cast(half2_t, w), b = __builtin_bit_cast(half2_t, h);
    return acc + (float)a[0]*(float)b[0] + (float)a[1]*(float)b[1];
#endif
}

#define RL(v, l) ((uint32_t)__builtin_amdgcn_readlane((int)(v), (l)))

__device__ __forceinline__ float fast_sigmoid(float x) {
    return __builtin_amdgcn_rcpf(1.f + __expf(-x));
}
__device__ __forceinline__ float fast_tanh(float x) {
    // 1 - 2/(e^{2x}+1); exact at +-inf via rcp(inf)=0
    return 1.f - 2.f*__builtin_amdgcn_rcpf(__expf(2.f*x) + 1.f);
}

// ---- pack input-projection weights [n<1024: wih_f | n>=1024: wih_b], K padded to 320, + fused bias
__global__ void k_pack_wih(const float* __restrict__ wih_f, const float* __restrict__ wih_b,
                           const float* __restrict__ bih_f, const float* __restrict__ bhh_f,
                           const float* __restrict__ bih_b, const float* __restrict__ bhh_b,
                           f16* __restrict__ wpack, float* __restrict__ bias2) {
    int n = blockIdx.x;
    const float* src = (n < G4H) ? (wih_f + (long)n*EDIM) : (wih_b + (long)(n-G4H)*EDIM);
    for (int k = threadIdx.x; k < KP; k += 64)
        wpack[(long)n*KP + k] = (k < EDIM) ? (f16)src[k] : (f16)0.f;
    if (threadIdx.x == 0)
        bias2[n] = (n < G4H) ? (bih_f[n] + bhh_f[n]) : (bih_b[n-G4H] + bhh_b[n-G4H]);
}

// ---- pack recurrent weights into [dir][k2][j] f16-pairs (k-pairs for v_dot2, j coalesced)
__global__ void k_pack_whh(const float* __restrict__ whh_f, const float* __restrict__ whh_b,
                           f16* __restrict__ whhp) {
    int fidx = blockIdx.x*256 + threadIdx.x;   // < 524288
    int d  = fidx >> 18;
    int r  = fidx & 262143;
    int k2 = r >> 11;
    int r2 = r & 2047;
    int j  = r2 >> 1;
    int p  = r2 & 1;
    const float* w = d ? whh_b : whh_f;
    whhp[fidx] = (f16)w[(long)j*HDIM + 2*k2 + p];
}

// ---- streamed-weight pack: whhs[dir][half][row][8 pairs] (per-thread contiguous,
// wave-dense 32 B/lane). Covers window pairs 56..63 (k2 = half*64 + 56 + p).
__global__ void k_pack_whhs(const float* __restrict__ whh_f, const float* __restrict__ whh_b,
                            uint32_t* __restrict__ whhs) {
    int f = blockIdx.x*256 + threadIdx.x;      // < 32768
    int p    = f & 7;
    int row  = (f >> 3) & 1023;
    int half = (f >> 13) & 1;
    int dir  = f >> 14;
    int k2 = half*64 + 56 + p;
    const float* w = dir ? whh_b : whh_f;
    f16 lo = (f16)w[(long)row*HDIM + 2*k2];
    f16 hi = (f16)w[(long)row*HDIM + 2*k2 + 1];
    whhs[f] = (uint32_t)__builtin_bit_cast(uint16_t, lo)
            | ((uint32_t)__builtin_bit_cast(uint16_t, hi) << 16);
}

// ---- embedding gather, f16, row m = t*64+b, padded to KP
__global__ void k_gather(const int* __restrict__ sentence, const float* __restrict__ embed,
                         f16* __restrict__ xg) {
    int m = blockIdx.x;
    int t = m >> 6, b = m & 63;
    int tok = sentence[b*SEQ + t];
    const float* row = embed + (long)tok*EDIM;
    for (int e = threadIdx.x; e < KP; e += 64)
        xg[(long)m*KP + e] = (e < EDIM) ? (f16)row[e] : (f16)0.f;
}

// ---- xproj = xg @ wpack^T + bias2, f16 MFMA GEMM, M=32768 N=2048 K=320
__launch_bounds__(256)
__global__ void k_gemm_xproj(const f16* __restrict__ xg, const f16* __restrict__ wpack,
                             const float* __restrict__ bias2, f16* __restrict__ xproj) {
    __shared__ __align__(16) f16 As[128*40];
    __shared__ __align__(16) f16 Bs[128*40];
    int tid = threadIdx.x;
    int bm = blockIdx.x, bn = blockIdx.y;
    int wid = tid >> 6, lane = tid & 63;
    int waveM = wid & 1, waveN = wid >> 1;
    int quad = lane >> 4, mlo = lane & 15;
    floatx4 acc[4][4] = {};
    for (int k0 = 0; k0 < KP; k0 += 32) {
        for (int it = 0; it < 2; ++it) {
            int c = tid + it*256;
            int row = c >> 2, ko = (c & 3)*8;
            *(uint4*)(&As[row*40 + ko]) = *(const uint4*)(&xg[(long)(bm*128+row)*KP + k0 + ko]);
            *(uint4*)(&Bs[row*40 + ko]) = *(const uint4*)(&wpack[(long)(bn*128+row)*KP + k0 + ko]);
        }
        __syncthreads();
        half8_t af[4], bf[4];
        #pragma unroll
        for (int i = 0; i < 4; ++i)
            af[i] = *(const half8_t*)(&As[(waveM*64 + i*16 + mlo)*40 + quad*8]);
        #pragma unroll
        for (int j = 0; j < 4; ++j)
            bf[j] = *(const half8_t*)(&Bs[(waveN*64 + j*16 + mlo)*40 + quad*8]);
        #pragma unroll
        for (int i = 0; i < 4; ++i)
            #pragma unroll
            for (int j = 0; j < 4; ++j)
                acc[i][j] = __builtin_amdgcn_mfma_f32_16x16x32_f16(af[i], bf[j], acc[i][j], 0, 0, 0);
        __syncthreads();
    }
    #pragma unroll
    for (int i = 0; i < 4; ++i)
        #pragma unroll
        for (int j = 0; j < 4; ++j) {
            int col = bn*128 + waveN*64 + j*16 + mlo;
            float bv = bias2[col];
            #pragma unroll
            for (int r = 0; r < 4; ++r) {
                int row = bm*128 + waveM*64 + i*16 + quad*4 + r;
                xproj[(long)row*NB + col] = (f16)(acc[i][j][r] + bv);
            }
        }
}

// ---- LSTM recurrence v7: WG = (dir, batch), 1024 threads, split-K.
// thread = (half of K, j<512): rows (j, j+512) over 64-pair window [half*64, half*64+64).
// Per row: 40 pairs VGPR + 16 pairs LDS (4 x b128) + 8 pairs streamed from L2
// (2 dense dwordx4, step-invariant addresses -> latency hidden).
// h-broadcast: 1 ds_read_b128 + 64 readlanes shared by the thread's 2 rows.
// Partials recombined via pbuf in epilogue. 4 waves/SIMD for latency hiding;
// per-thread pressure ~115 regs fits the 128-reg budget (waves_per_eu(4,4)).
#define VREG 40   // VGPR pairs per row
#define WLQ  4    // LDS quads per row (16 pairs)
__attribute__((amdgpu_waves_per_eu(4, 4)))
__global__ void __launch_bounds__(1024) k_recur(const f16* __restrict__ xproj,
                                                const f16* __restrict__ whhp,
                                                const uint32_t* __restrict__ whhs,
                                                f16* __restrict__ hcat) {
    __shared__ uint4 wlds[2*WLQ][1024];  // 128 KB: q<4 rowA pairs40+, q>=4 rowB
    __shared__ float2 pbuf[1024];        // 8 KB partial sums (rowA, rowB)
    __shared__ uint32_t hpair[128];      // h as f16 pairs
    int dir = blockIdx.x & 1, b = blockIdx.x >> 1;
    int tid = threadIdx.x, lane = tid & 63;
    int half = tid >> 9;                 // wave-uniform (waves 0-7 vs 8-15)
    int j = tid & 511;
    int rA = j, rB = j + 512;            // (i|f) row and (g|o) row
    const uint32_t* base = (const uint32_t*)whhp + (long)dir*131072 + (long)(half*64)*1024;
    uint32_t wregA[VREG], wregB[VREG];
    #pragma unroll
    for (int i = 0; i < VREG; ++i) {
        wregA[i] = base[(long)i*1024 + rA];
        wregB[i] = base[(long)i*1024 + rB];
    }
    #pragma unroll
    for (int i = 0; i < VREG; ++i) { asm volatile("" : "+v"(wregA[i]), "+v"(wregB[i])); }
    #pragma unroll
    for (int q = 0; q < WLQ; ++q) {
        uint4 wa, wb;
        wa.x = base[(long)(VREG+4*q+0)*1024 + rA]; wa.y = base[(long)(VREG+4*q+1)*1024 + rA];
        wa.z = base[(long)(VREG+4*q+2)*1024 + rA]; wa.w = base[(long)(VREG+4*q+3)*1024 + rA];
        wb.x = base[(long)(VREG+4*q+0)*1024 + rB]; wb.y = base[(long)(VREG+4*q+1)*1024 + rB];
        wb.z = base[(long)(VREG+4*q+2)*1024 + rB]; wb.w = base[(long)(VREG+4*q+3)*1024 + rB];
        wlds[q][tid] = wa;
        wlds[WLQ+q][tid] = wb;
    }
    const uint4* wsA = (const uint4*)(whhs + (((long)(dir*2 + half)*1024 + rA)*8));
    const uint4* wsB = (const uint4*)(whhs + (((long)(dir*2 + half)*1024 + rB)*8));
    const f16* xA = xproj + dir*G4H + rA;
    const f16* xB = xproj + dir*G4H + rB;
    float c = 0.f;
    if (tid < 128) hpair[tid] = 0u;
    __syncthreads();
    long dstep = dir ? -64 : 64;
    long mrow = (long)((dir ? SEQ-1 : 0)*64 + b);
    float xvA = 0.f, xvB = 0.f;
    if (half == 0) { xvA = (float)xA[mrow*NB]; xvB = (float)xB[mrow*NB]; }
    for (int s = 0; s < SEQ; ++s) {
        uint4 sA0 = wsA[0], sA1 = wsA[1];      // streamed pairs 56..63 (L2, step-inv)
        uint4 sB0 = wsB[0], sB1 = wsB[1];
        long mnext = (s+1 < SEQ) ? (mrow + dstep) : mrow;
        float xnA = 0.f, xnB = 0.f;
        if (half == 0) { xnA = (float)xA[mnext*NB]; xnB = (float)xB[mnext*NB]; }
        uint4 hq = ((const uint4*)hpair)[half*16 + (lane & 15)];  // quads half*16+q
        float aA0=0.f, aA1=0.f, aB0=0.f, aB1=0.f;
        #pragma unroll
        for (int qq = 0; qq < VREG/4; ++qq) {          // window pairs 0..39 (VGPR)
            uint32_t h0 = RL(hq.x, qq), h1 = RL(hq.y, qq);
            uint32_t h2 = RL(hq.z, qq), h3 = RL(hq.w, qq);
            aA0 = fdot2(wregA[4*qq+0], h0, aA0); aB0 = fdot2(wregB[4*qq+0], h0, aB0);
            aA1 = fdot2(wregA[4*qq+1], h1, aA1); aB1 = fdot2(wregB[4*qq+1], h1, aB1);
            aA0 = fdot2(wregA[4*qq+2], h2, aA0); aB0 = fdot2(wregB[4*qq+2], h2, aB0);
            aA1 = fdot2(wregA[4*qq+3], h3, aA1); aB1 = fdot2(wregB[4*qq+3], h3, aB1);
        }
        #pragma unroll
        for (int q = 0; q < WLQ; ++q) {                // window pairs 40..55 (LDS)
            int qq = VREG/4 + q;
            uint4 wa = wlds[q][tid], wb = wlds[WLQ+q][tid];
            uint32_t h0 = RL(hq.x, qq), h1 = RL(hq.y, qq);
            uint32_t h2 = RL(hq.z, qq), h3 = RL(hq.w, qq);
            aA0 = fdot2(wa.x, h0, aA0); aB0 = fdot2(wb.x, h0, aB0);
            aA1 = fdot2(wa.y, h1, aA1); aB1 = fdot2(wb.y, h1, aB1);
            aA0 = fdot2(wa.z, h2, aA0); aB0 = fdot2(wb.z, h2, aB0);
            aA1 = fdot2(wa.w, h3, aA1); aB1 = fdot2(wb.w, h3, aB1);
        }
        {                                              // window pairs 56..63 (streamed)
            uint32_t h0 = RL(hq.x, 14), h1 = RL(hq.y, 14);
            uint32_t h2 = RL(hq.z, 14), h3 = RL(hq.w, 14);
            aA0 = fdot2(sA0.x, h0, aA0); aB0 = fdot2(sB0.x, h0, aB0);
            aA1 = fdot2(sA0.y, h1, aA1); aB1 = fdot2(sB0.y, h1, aB1);
            aA0 = fdot2(sA0.z, h2, aA0); aB0 = fdot2(sB0.z, h2, aB0);
            aA1 = fdot2(sA0.w, h3, aA1); aB1 = fdot2(sB0.w, h3, aB1);
            h0 = RL(hq.x, 15); h1 = RL(hq.y, 15);
            h2 = RL(hq.z, 15); h3 = RL(hq.w, 15);
            aA0 = fdot2(sA1.x, h0, aA0); aB0 = fdot2(sB1.x, h0, aB0);
            aA1 = fdot2(sA1.y, h1, aA1); aB1 = fdot2(sB1.y, h1, aB1);
            aA0 = fdot2(sA1.z, h2, aA0); aB0 = fdot2(sB1.z, h2, aB0);
            aA1 = fdot2(sA1.w, h3, aA1); aB1 = fdot2(sB1.w, h3, aB1);
        }
        pbuf[tid] = make_float2(aA0 + aA1 + xvA, aB0 + aB1 + xvB);
        xvA = xnA; xvB = xnB;
        __syncthreads();               // pbuf complete; hq reads done
        f16 hh;
        if (tid < 256) {
            float2 p0 = pbuf[tid],       p1 = pbuf[tid+256];
            float2 p2 = pbuf[tid+512],   p3 = pbuf[tid+768];
            float gi = p0.x + p2.x, gf = p1.x + p3.x;   // rows u, 256+u
            float gg = p0.y + p2.y, go = p1.y + p3.y;   // rows 512+u, 768+u
            float si = fast_sigmoid(gi), sf = fast_sigmoid(gf), so = fast_sigmoid(go);
            c = sf*c + si*fast_tanh(gg);
            float h = so*fast_tanh(c);
            hh = (f16)h;
            ((f16*)hpair)[tid] = hh;
        }
        __syncthreads();               // new h visible before next step
        if (tid < 256)
            hcat[mrow*512 + dir*HDIM + tid] = hh;
        mrow += dstep;
    }
}

// ---- emissions: one wave per (t,b) row; lanes split K=512; 9 shuffle-reduced dots.
// Output laid out b-major [b][t][tag] so k_crf's serial t-loop reads sequentially.
__launch_bounds__(256)
__global__ void k_emis(const f16* __restrict__ hcat, const float* __restrict__ w_out,
                       const float* __restrict__ b_out, float* __restrict__ emis) {
    int r = blockIdx.x*4 + (threadIdx.x >> 6);
    int lane = threadIdx.x & 63;
    int t = r >> 6, b = r & 63;
    float hv[8];
    #pragma unroll
    for (int i = 0; i < 8; ++i) hv[i] = (float)hcat[(long)r*512 + lane + i*64];
    for (int tag = 0; tag < TAGS; ++tag) {
        float acc = 0.f;
        #pragma unroll
        for (int i = 0; i < 8; ++i) acc += hv[i]*w_out[tag*512 + lane + i*64];
        for (int off = 32; off; off >>= 1) acc += __shfl_xor(acc, off);
        if (lane == 0) emis[((long)b*SEQ + t)*TAGS + tag] = acc + b_out[tag];
    }
}

// ---- CRF: one wave per batch row; emis is b-major (sequential 36-B windows -> L1 hits).
__launch_bounds__(256)
__global__ void k_crf(const float* __restrict__ emis, const int* __restrict__ tags,
                      const int* __restrict__ mask, const float* __restrict__ start_trans,
                      const float* __restrict__ end_trans, const float* __restrict__ trans,
                      float* __restrict__ out) {
    int b = blockIdx.x*4 + (threadIdx.x >> 6);
    int lane = threadIdx.x & 63;
    int len = 0;
    #pragma unroll
    for (int i = 0; i < 8; ++i) len += mask[b*SEQ + lane + i*64];
    for (int off = 32; off; off >>= 1) len += __shfl_xor(len, off);
    float sc = 0.f;
    for (int i = 0; i < 8; ++i) {
        int t = 1 + lane + i*64;
        if (t < SEQ && mask[b*SEQ + t]) {
            int tp = tags[b*SEQ + t - 1], tc = tags[b*SEQ + t];
            sc += trans[tp*TAGS + tc] + emis[((long)b*SEQ + t)*TAGS + tc];
        }
    }
    for (int off = 32; off; off >>= 1) sc += __shfl_xor(sc, off);
    int tag0 = tags[b*SEQ];
    sc += start_trans[tag0] + emis[(long)b*SEQ*TAGS + tag0];
    sc += end_trans[tags[b*SEQ + len - 1]];
    // logZ
    bool act = lane < TAGS;
    int j = act ? lane : 0;
    float tcol[TAGS];
    #pragma unroll
    for (int i = 0; i < TAGS; ++i) tcol[i] = trans[i*TAGS + j];
    float alpha = act ? (start_trans[j] + emis[(long)b*SEQ*TAGS + j]) : -1e30f;
    for (int t = 1; t < SEQ; ++t) {
        int mt = mask[b*SEQ + t];
        float em = emis[((long)b*SEQ + t)*TAGS + j];
        float v[TAGS], mx = -1e30f;
        #pragma unroll
        for (int i = 0; i < TAGS; ++i) { v[i] = __shfl(alpha, i) + tcol[i]; mx = fmaxf(mx, v[i]); }
        float ss = 0.f;
        #pragma unroll
        for (int i = 0; i < TAGS; ++i) ss += __expf(v[i] - mx);
        float nxt = mx + __logf(ss) + em;
        if (mt && act) alpha = nxt;
    }
    float fv = act ? (alpha + end_trans[j]) : -1e30f;
    float mx = fv;
    for (int off = 32; off; off >>= 1) mx = fmaxf(mx, __shfl_xor(mx, off));
    float ss = act ? __expf(fv - mx) : 0.f;
    for (int off = 32; off; off >>= 1) ss += __shfl_xor(ss, off);
    float logZ = mx + __logf(ss);
    if (lane == 0) atomicAdd(out, (logZ - sc) * (1.0f/BATCH));
}

extern "C" void kernel_launch(void* const* d_in, const int* in_sizes, int n_in,
                              void* d_out, int out_size, void* d_ws, size_t ws_size,
                              hipStream_t stream) {
    const int*   sentence    = (const int*)  d_in[0];
    const int*   tags        = (const int*)  d_in[1];
    const float* embed       = (const float*)d_in[2];
    const float* wih_f       = (const float*)d_in[3];
    const float* whh_f       = (const float*)d_in[4];
    const float* bih_f       = (const float*)d_in[5];
    const float* bhh_f       = (const float*)d_in[6];
    const float* wih_b       = (const float*)d_in[7];
    const float* whh_b       = (const float*)d_in[8];
    const float* bih_b       = (const float*)d_in[9];
    const float* bhh_b       = (const float*)d_in[10];
    const float* w_out       = (const float*)d_in[11];
    const float* b_out       = (const float*)d_in[12];
    const float* start_trans = (const float*)d_in[13];
    const float* end_trans   = (const float*)d_in[14];
    const float* trans       = (const float*)d_in[15];
    const int*   mask        = (const int*)  d_in[16];

    char* ws = (char*)d_ws;
    f16*      xg    = (f16*)ws;      ws += (size_t)MROWS*KP*2;      // 20.97 MB
    f16*      wpack = (f16*)ws;      ws += (size_t)NB*KP*2;         // 1.31 MB
    float*    bias2 = (float*)ws;    ws += (size_t)NB*4;            // 8 KB
    f16*      whhp  = (f16*)ws;      ws += (size_t)2*262144*2;      // 1.05 MB
    uint32_t* whhs  = (uint32_t*)ws; ws += (size_t)32768*4;         // 128 KB
    f16*      xproj = (f16*)ws;      ws += (size_t)MROWS*NB*2;      // 134.2 MB
    f16*      hcat  = (f16*)ws;      ws += (size_t)MROWS*512*2;     // 33.55 MB
    float*    emis  = (float*)ws;    ws += (size_t)MROWS*TAGS*4;    // 1.18 MB

    hipLaunchKernelGGL(k_pack_wih, dim3(NB), dim3(64), 0, stream,
                       wih_f, wih_b, bih_f, bhh_f, bih_b, bhh_b, wpack, bias2);
    hipLaunchKernelGGL(k_pack_whh, dim3(2048), dim3(256), 0, stream, whh_f, whh_b, whhp);
    hipLaunchKernelGGL(k_pack_whhs, dim3(128), dim3(256), 0, stream, whh_f, whh_b, whhs);
    hipLaunchKernelGGL(k_gather, dim3(MROWS), dim3(64), 0, stream, sentence, embed, xg);
    hipLaunchKernelGGL(k_gemm_xproj, dim3(256,16), dim3(256), 0, stream, xg, wpack, bias2, xproj);
    hipLaunchKernelGGL(k_recur, dim3(128), dim3(1024), 0, stream, xproj, whhp, whhs, hcat);
    hipLaunchKernelGGL(k_emis, dim3(MROWS/4), dim3(256), 0, stream, hcat, w_out, b_out, emis);
    hipMemsetAsync(d_out, 0, sizeof(float), stream);
    hipLaunchKernelGGL(k_crf, dim3(BATCH/4), dim3(256), 0, stream,
                       emis, tags, mask, start_trans, end_trans, trans, (float*)d_out);
}